// Round 9
// baseline (469.643 us; speedup 1.0000x reference)
//
#include <hip/hip_runtime.h>
#include <hip/hip_bf16.h>
#include <hip/hip_fp16.h>
#include <float.h>

#define HEADS 4
#define DK 32

static constexpr float kBeta = 1.0f;
static constexpr float kNeg  = 0.2f;
static constexpr float kEps  = 1e-12f;

typedef __bf16 bf16x8 __attribute__((ext_vector_type(8)));
typedef float  f32x4  __attribute__((ext_vector_type(4)));

__device__ __forceinline__ float bf2f(unsigned short v) {
  return __uint_as_float((unsigned)v << 16);
}
// round-to-nearest-even f32 -> bf16 bits
__device__ __forceinline__ unsigned short f2bf(float f) {
  unsigned u = __float_as_uint(f);
  unsigned r = u + 0x7FFFu + ((u >> 16) & 1u);
  return (unsigned short)(r >> 16);
}
// order-preserving float <-> uint key for atomicMax
__device__ __forceinline__ unsigned fkey(float x) {
  unsigned u = __float_as_uint(x);
  return (u & 0x80000000u) ? ~u : (u | 0x80000000u);
}
__device__ __forceinline__ float funkey(unsigned k) {
  unsigned u = (k & 0x80000000u) ? (k & 0x7fffffffu) : ~k;
  return __uint_as_float(u);
}
__device__ __forceinline__ bf16x8 as8(uint4 v) {
  union { uint4 u; bf16x8 b; } x; x.u = v; return x.b;
}

// ---- K0a: fused detect: edge layout (int64 -> odd words 0) + float dtype -----
__global__ __launch_bounds__(256) void k_detect(const int* __restrict__ ei32,
                                                const unsigned* __restrict__ Hw,
                                                int* __restrict__ eflag,
                                                int* __restrict__ dflag,
                                                int E, int nw) {
  int i = blockIdx.x * 256 + threadIdx.x;
  if (i < 4096 && 2 * i + 1 < 2 * E && ei32[2 * i + 1] != 0) atomicOr(eflag, 1);
  if (i < nw && ((Hw[i] >> 7) & 0xFFu) == 0xFFu) atomicOr(dflag, 1);
}

// ---- K0c: normalize edge index into int32 src/dst + degree histogram ---------
__global__ __launch_bounds__(256) void k_cvt(const int* __restrict__ ei32,
                                             const int* __restrict__ eflag,
                                             int* __restrict__ src_i,
                                             int* __restrict__ dst_i,
                                             int* __restrict__ deg, int E) {
  int i = blockIdx.x * 256 + threadIdx.x;
  if (i >= E) return;
  int s, d;
  if (*eflag) { s = ei32[i];     d = ei32[E + i]; }
  else        { s = ei32[2 * i]; d = ei32[2 * E + 2 * i]; }
  src_i[i] = s;
  dst_i[i] = d;
  atomicAdd(deg + d, 1);
}

// ---- K0d: W -> MFMA B-fragment pack (hi/lo bf16 split) + small params --------
__global__ __launch_bounds__(256) void k_wparams(const void* __restrict__ in,
                                                 unsigned short* __restrict__ Bhi,
                                                 unsigned short* __restrict__ Blo,
                                                 const void* __restrict__ a_src,
                                                 const void* __restrict__ a_dst,
                                                 const void* __restrict__ msg_w,
                                                 float* __restrict__ af,
                                                 float* __restrict__ msgwf,
                                                 const int* __restrict__ dflag) {
  const int dt = *dflag;
  if (blockIdx.x < 128) {
    int i = blockIdx.x * 256 + threadIdx.x;  // i = r*256 + c, r: out-col, c: k
    int r = i >> 8, c = i & 255;
    float v = dt ? ((const float*)in)[i] : bf2f(((const unsigned short*)in)[i]);
    unsigned short hb = f2bf(v);
    unsigned short lb = f2bf(v - bf2f(hb));
    int kt = c >> 5, ct = r >> 4;
    int lane = (((c >> 3) & 3) << 4) | (r & 15);
    int idx = ((kt * 8 + ct) * 64 + lane) * 8 + (c & 7);
    Bhi[idx] = hb;
    Blo[idx] = lb;
  } else {
    int i = (blockIdx.x - 128) * 256 + threadIdx.x;  // [0, 1280)
    if (i < 128) {
      af[i] = dt ? ((const float*)a_src)[i] : bf2f(((const unsigned short*)a_src)[i]);
    } else if (i < 256) {
      int j = i - 128;
      af[i] = dt ? ((const float*)a_dst)[j] : bf2f(((const unsigned short*)a_dst)[j]);
    } else if (i < 1280) {
      int j = i - 256;
      msgwf[j] = dt ? ((const float*)msg_w)[j] : bf2f(((const unsigned short*)msg_w)[j]);
    }
  }
}

// ---- K0e: 3-phase device-wide exclusive scan of deg --------------------------
__global__ __launch_bounds__(256) void k_scan1(const int* __restrict__ deg,
                                               int* __restrict__ bsum, int N) {
  const int t = threadIdx.x;
  int i = blockIdx.x * 256 + t;
  int v = (i < N) ? deg[i] : 0;
#pragma unroll
  for (int off = 32; off; off >>= 1) v += __shfl_xor(v, off);
  __shared__ int red[4];
  if ((t & 63) == 0) red[t >> 6] = v;
  __syncthreads();
  if (t == 0) bsum[blockIdx.x] = red[0] + red[1] + red[2] + red[3];
}
__global__ __launch_bounds__(1024) void k_scan2(int* __restrict__ bsum, int nb) {
  __shared__ int part[1024];
  const int t = threadIdx.x;
  part[t] = (t < nb) ? bsum[t] : 0;
  __syncthreads();
  int own = part[t];
  for (int off = 1; off < 1024; off <<= 1) {
    int v = (t >= off) ? part[t - off] : 0;
    __syncthreads();
    part[t] += v;
    __syncthreads();
  }
  if (t < nb) bsum[t] = part[t] - own;  // exclusive block offset
}
__global__ __launch_bounds__(256) void k_scan3(const int* __restrict__ deg,
                                               const int* __restrict__ bsum,
                                               int* __restrict__ row_ptr,
                                               int* __restrict__ cursor, int N) {
  __shared__ int part[256];
  const int t = threadIdx.x;
  int i = blockIdx.x * 256 + t;
  int v = (i < N) ? deg[i] : 0;
  part[t] = v;
  __syncthreads();
  for (int off = 1; off < 256; off <<= 1) {
    int x = (t >= off) ? part[t - off] : 0;
    __syncthreads();
    part[t] += x;
    __syncthreads();
  }
  int excl = part[t] - v + bsum[blockIdx.x];
  if (i < N) {
    row_ptr[i] = excl;
    cursor[i]  = excl;
    if (i == N - 1) row_ptr[N] = excl + v;
  }
}

// ---- K1: H_proj GEMM via MFMA; B staged through LDS (2 half-passes) ----------
__global__ __launch_bounds__(256) void k_proj(const void* __restrict__ Hraw,
                                              const unsigned short* __restrict__ Bhi,
                                              const unsigned short* __restrict__ Blo,
                                              const int* __restrict__ dflag,
                                              const float* __restrict__ af,
                                              const float* __restrict__ msgwf,
                                              float* __restrict__ s_src,
                                              float* __restrict__ s_dst,
                                              __half* __restrict__ msgb,
                                              __half* __restrict__ Hb, int N) {
  __shared__ uint4 ldsA[2048];  // 32KB A frags (also epilogue scratch)
  __shared__ uint4 ldsB[2048];  // 32KB B half-table (bf16 path)
  float* ldsF = (float*)ldsA;
  const int t = threadIdx.x;
  const int nb = blockIdx.x * 64;
  const int dt = *dflag;
  const int l = t & 63;
  const int wv = t >> 6;
  const int wrow = wv * 16;
  const int c16 = l & 15;
  const int g4 = l >> 4;

  f32x4 acc[8];
#pragma unroll
  for (int ct = 0; ct < 8; ++ct) acc[ct] = (f32x4){0.f, 0.f, 0.f, 0.f};
  const uint4* __restrict__ Bh4 = (const uint4*)Bhi;
  const uint4* __restrict__ Bl4 = (const uint4*)Blo;

  if (!dt) {
    // ======== bf16 path: A exact; B via LDS, two half-passes ========
    const uint4* __restrict__ H8 = (const uint4*)Hraw;
#pragma unroll
    for (int it = 0; it < 8; ++it) {
      int c = it * 256 + t;
      int row = c >> 5, k8 = c & 31;
      int gr = nb + row;
      uint4 v = make_uint4(0u, 0u, 0u, 0u);
      if (gr < N) v = H8[(size_t)gr * 32 + k8];
      ldsA[(k8 * 64 + row) ^ (k8 & 7)] = v;
    }
#pragma unroll
    for (int it = 0; it < 8; ++it) ldsB[it * 256 + t] = Bh4[it * 256 + t];  // kt 0..3
    __syncthreads();
#pragma unroll
    for (int kt = 0; kt < 4; ++kt) {
      int k8 = kt * 4 + g4;
      int slot = (k8 * 64 + wrow + c16) ^ (k8 & 7);
      bf16x8 ah = as8(ldsA[slot]);
#pragma unroll
      for (int ct = 0; ct < 8; ++ct) {
        bf16x8 bh = as8(ldsB[(kt * 8 + ct) * 64 + l]);
        acc[ct] = __builtin_amdgcn_mfma_f32_16x16x32_bf16(ah, bh, acc[ct], 0, 0, 0);
      }
    }
    __syncthreads();
#pragma unroll
    for (int it = 0; it < 8; ++it) ldsB[it * 256 + t] = Bh4[2048 + it * 256 + t];  // kt 4..7
    __syncthreads();
#pragma unroll
    for (int kt = 4; kt < 8; ++kt) {
      int k8 = kt * 4 + g4;
      int slot = (k8 * 64 + wrow + c16) ^ (k8 & 7);
      bf16x8 ah = as8(ldsA[slot]);
#pragma unroll
      for (int ct = 0; ct < 8; ++ct) {
        bf16x8 bh = as8(ldsB[((kt - 4) * 8 + ct) * 64 + l]);
        acc[ct] = __builtin_amdgcn_mfma_f32_16x16x32_bf16(ah, bh, acc[ct], 0, 0, 0);
      }
    }
  } else {
    // ======== fp32 path (cold): hi/lo two-pass over A, B from L2 ========
    const float4* __restrict__ H4 = (const float4*)Hraw;
#pragma unroll
    for (int it = 0; it < 8; ++it) {
      int c = it * 256 + t;
      int row = c >> 5, k8 = c & 31;
      int gr = nb + row;
      float4 v0 = make_float4(0.f, 0.f, 0.f, 0.f), v1 = v0;
      if (gr < N) {
        v0 = H4[(size_t)gr * 64 + k8 * 2];
        v1 = H4[(size_t)gr * 64 + k8 * 2 + 1];
      }
      float f[8] = {v0.x, v0.y, v0.z, v0.w, v1.x, v1.y, v1.z, v1.w};
      unsigned hi[8];
#pragma unroll
      for (int j = 0; j < 8; ++j) hi[j] = f2bf(f[j]);
      ldsA[(k8 * 64 + row) ^ (k8 & 7)] =
          make_uint4(hi[0] | (hi[1] << 16), hi[2] | (hi[3] << 16),
                     hi[4] | (hi[5] << 16), hi[6] | (hi[7] << 16));
    }
    __syncthreads();
#pragma unroll 2
    for (int kt = 0; kt < 8; ++kt) {
      int k8 = kt * 4 + g4;
      int slot = (k8 * 64 + wrow + c16) ^ (k8 & 7);
      bf16x8 ah = as8(ldsA[slot]);
#pragma unroll
      for (int ct = 0; ct < 8; ++ct) {
        bf16x8 bh = as8(Bh4[(kt * 8 + ct) * 64 + l]);
        acc[ct] = __builtin_amdgcn_mfma_f32_16x16x32_bf16(ah, bh, acc[ct], 0, 0, 0);
        bf16x8 bl = as8(Bl4[(kt * 8 + ct) * 64 + l]);
        acc[ct] = __builtin_amdgcn_mfma_f32_16x16x32_bf16(ah, bl, acc[ct], 0, 0, 0);
      }
    }
    __syncthreads();
#pragma unroll
    for (int it = 0; it < 8; ++it) {
      int c = it * 256 + t;
      int row = c >> 5, k8 = c & 31;
      int gr = nb + row;
      float4 v0 = make_float4(0.f, 0.f, 0.f, 0.f), v1 = v0;
      if (gr < N) {
        v0 = H4[(size_t)gr * 64 + k8 * 2];
        v1 = H4[(size_t)gr * 64 + k8 * 2 + 1];
      }
      float f[8] = {v0.x, v0.y, v0.z, v0.w, v1.x, v1.y, v1.z, v1.w};
      unsigned lo[8];
#pragma unroll
      for (int j = 0; j < 8; ++j) lo[j] = f2bf(f[j] - bf2f(f2bf(f[j])));
      ldsA[(k8 * 64 + row) ^ (k8 & 7)] =
          make_uint4(lo[0] | (lo[1] << 16), lo[2] | (lo[3] << 16),
                     lo[4] | (lo[5] << 16), lo[6] | (lo[7] << 16));
    }
    __syncthreads();
#pragma unroll 2
    for (int kt = 0; kt < 8; ++kt) {
      int k8 = kt * 4 + g4;
      int slot = (k8 * 64 + wrow + c16) ^ (k8 & 7);
      bf16x8 al = as8(ldsA[slot]);
#pragma unroll
      for (int ct = 0; ct < 8; ++ct) {
        bf16x8 bh = as8(Bh4[(kt * 8 + ct) * 64 + l]);
        acc[ct] = __builtin_amdgcn_mfma_f32_16x16x32_bf16(al, bh, acc[ct], 0, 0, 0);
      }
    }
  }
  __syncthreads();  // all staging reads done; reuse ldsA for epilogue

  // ---- epilogue (registers + small LDS, fully parallel) ----
  // acc layout: lane l: row = nb + wrow + g4*4 + r, col = ct*16 + c16  [m89]
#pragma unroll
  for (int i = 0; i < 4; ++i) {
    int idx = t * 4 + i;
    ldsF[(idx >> 5) * 33 + (idx & 31)] = msgwf[idx];
  }
  float* hbuf = ldsF + 1056 + wv * 528;  // [16 rows][33]
#pragma unroll
  for (int r = 0; r < 4; ++r) {
    float h0 = 0.25f * (acc[0][r] + acc[2][r] + acc[4][r] + acc[6][r]);
    float h1 = 0.25f * (acc[1][r] + acc[3][r] + acc[5][r] + acc[7][r]);
    hbuf[(g4 * 4 + r) * 33 + c16]      = h0;
    hbuf[(g4 * 4 + r) * 33 + 16 + c16] = h1;
  }
  __syncthreads();

  float afp[8], afq[8];
#pragma unroll
  for (int ct = 0; ct < 8; ++ct) {
    afp[ct] = af[ct * 16 + c16];
    afq[ct] = af[128 + ct * 16 + c16];
  }
  float pv0[4], pv1[4], pv2[4], pv3[4], qv0[4], qv1[4], qv2[4], qv3[4];
#pragma unroll
  for (int r = 0; r < 4; ++r) {
    pv0[r] = acc[0][r] * afp[0] + acc[1][r] * afp[1];
    pv1[r] = acc[2][r] * afp[2] + acc[3][r] * afp[3];
    pv2[r] = acc[4][r] * afp[4] + acc[5][r] * afp[5];
    pv3[r] = acc[6][r] * afp[6] + acc[7][r] * afp[7];
    qv0[r] = acc[0][r] * afq[0] + acc[1][r] * afq[1];
    qv1[r] = acc[2][r] * afq[2] + acc[3][r] * afq[3];
    qv2[r] = acc[4][r] * afq[4] + acc[5][r] * afq[5];
    qv3[r] = acc[6][r] * afq[6] + acc[7][r] * afq[7];
  }
#pragma unroll
  for (int off = 1; off <= 8; off <<= 1) {
#pragma unroll
    for (int r = 0; r < 4; ++r) {
      pv0[r] += __shfl_xor(pv0[r], off);
      pv1[r] += __shfl_xor(pv1[r], off);
      pv2[r] += __shfl_xor(pv2[r], off);
      pv3[r] += __shfl_xor(pv3[r], off);
      qv0[r] += __shfl_xor(qv0[r], off);
      qv1[r] += __shfl_xor(qv1[r], off);
      qv2[r] += __shfl_xor(qv2[r], off);
      qv3[r] += __shfl_xor(qv3[r], off);
    }
  }
#pragma unroll
  for (int r = 0; r < 4; ++r) {
    int n = nb + wrow + g4 * 4 + r;
    if (n < N) {
      if (c16 < 4) {
        float v = (c16 == 0) ? pv0[r] : (c16 == 1) ? pv1[r]
                 : (c16 == 2) ? pv2[r] : pv3[r];
        s_src[(size_t)n * 4 + c16] = v;
      } else if (c16 < 8) {
        int hh = c16 - 4;
        float v = (hh == 0) ? qv0[r] : (hh == 1) ? qv1[r]
                 : (hh == 2) ? qv2[r] : qv3[r];
        s_dst[(size_t)n * 4 + hh] = v;
      }
    }
  }
#pragma unroll
  for (int ct = 0; ct < 8; ++ct) {
#pragma unroll
    for (int r = 0; r < 4; ++r) {
      int n = nb + wrow + g4 * 4 + r;
      if (n < N) Hb[(size_t)n * 128 + ct * 16 + c16] = __float2half(acc[ct][r]);
    }
  }
  {
    const int j = l & 31;
    const int r0 = (l >> 5) * 8;
    float res[8] = {0.f, 0.f, 0.f, 0.f, 0.f, 0.f, 0.f, 0.f};
#pragma unroll 4
    for (int d = 0; d < 32; ++d) {
      float mw = ldsF[j * 33 + d];
#pragma unroll
      for (int i = 0; i < 8; ++i) res[i] += hbuf[(r0 + i) * 33 + d] * mw;
    }
#pragma unroll
    for (int i = 0; i < 8; ++i) {
      int n = nb + wrow + r0 + i;
      if (n < N) msgb[(size_t)n * 32 + j] = __float2half(res[i]);
    }
  }
}

// ---- K3: CSR fill + (src,sim) pack + per-head global max ---------------------
__global__ __launch_bounds__(256) void k_fillog(const int* __restrict__ src,
                                                const int* __restrict__ dstv,
                                                const void* __restrict__ sim1,
                                                const int* __restrict__ dflag,
                                                const float* __restrict__ s_src,
                                                const float* __restrict__ s_dst,
                                                int* __restrict__ cursor,
                                                int2* __restrict__ pack,
                                                unsigned* __restrict__ gmax, int E) {
  const int e = blockIdx.x * 256 + threadIdx.x;
  float m0 = -FLT_MAX, m1 = -FLT_MAX, m2 = -FLT_MAX, m3 = -FLT_MAX;
  if (e < E) {
    int s = src[e], d = dstv[e];
    float sv = (*dflag) ? ((const float*)sim1)[e] : bf2f(((const unsigned short*)sim1)[e]);
    int pos = atomicAdd(cursor + d, 1);
    pack[pos] = make_int2(s, __float_as_int(sv));
    float4 ss = *(const float4*)(s_src + (size_t)s * 4);
    float4 sd = *(const float4*)(s_dst + (size_t)d * 4);
    float b = kBeta * sv;
    float e0 = ss.x + sd.x + b; e0 = (e0 >= 0.f) ? e0 : kNeg * e0;
    float e1 = ss.y + sd.y + b; e1 = (e1 >= 0.f) ? e1 : kNeg * e1;
    float e2 = ss.z + sd.z + b; e2 = (e2 >= 0.f) ? e2 : kNeg * e2;
    float e3 = ss.w + sd.w + b; e3 = (e3 >= 0.f) ? e3 : kNeg * e3;
    m0 = e0; m1 = e1; m2 = e2; m3 = e3;
  }
#pragma unroll
  for (int off = 32; off; off >>= 1) {
    m0 = fmaxf(m0, __shfl_xor(m0, off));
    m1 = fmaxf(m1, __shfl_xor(m1, off));
    m2 = fmaxf(m2, __shfl_xor(m2, off));
    m3 = fmaxf(m3, __shfl_xor(m3, off));
  }
  __shared__ float red[4][4];
  if ((threadIdx.x & 63) == 0) {
    int w = threadIdx.x >> 6;
    red[w][0] = m0; red[w][1] = m1; red[w][2] = m2; red[w][3] = m3;
  }
  __syncthreads();
  if (threadIdx.x < 4) {
    int h = threadIdx.x;
    float mm = fmaxf(fmaxf(red[0][h], red[1][h]), fmaxf(red[2][h], red[3][h]));
    atomicMax(gmax + h, fkey(mm));
  }
}

// ---- K5: wave-per-node CSR gather: denom + out rows (no alpha scatter) -------
__global__ __launch_bounds__(256) void k_out(const int* __restrict__ row_ptr,
                                             const int2* __restrict__ pack,
                                             const float* __restrict__ s_src,
                                             const float* __restrict__ s_dst,
                                             const unsigned* __restrict__ gmax,
                                             const unsigned* __restrict__ Hb_u,
                                             const int* __restrict__ dflag,
                                             float* __restrict__ denom,
                                             void* __restrict__ d_out, int N) {
  const int n = (int)((blockIdx.x * 256 + threadIdx.x) >> 6);
  const int l = threadIdx.x & 63;
  if (n >= N) return;
  const int beg = row_ptr[n];
  const int deg = row_ptr[n + 1] - beg;
  const int dt = *dflag;
  const float m0 = funkey(gmax[0]), m1 = funkey(gmax[1]);
  const float m2 = funkey(gmax[2]), m3 = funkey(gmax[3]);
  const float4 sd = *(const float4*)(s_dst + (size_t)n * 4);  // wave-uniform
  float accx = 0.f, accy = 0.f;
  float4 dn = make_float4(0.f, 0.f, 0.f, 0.f);
  int s = 0;
  float4 ev = make_float4(0.f, 0.f, 0.f, 0.f);
  const bool small = (deg <= 64);
  if (small) {
    if (l < deg) {
      int2 p = pack[beg + l];
      s = p.x;
      float sv = __int_as_float(p.y);
      float4 ss = *(const float4*)(s_src + (size_t)s * 4);
      float e0 = ss.x + sd.x + sv; e0 = (e0 >= 0.f) ? e0 : kNeg * e0;
      float e1 = ss.y + sd.y + sv; e1 = (e1 >= 0.f) ? e1 : kNeg * e1;
      float e2 = ss.z + sd.z + sv; e2 = (e2 >= 0.f) ? e2 : kNeg * e2;
      float e3 = ss.w + sd.w + sv; e3 = (e3 >= 0.f) ? e3 : kNeg * e3;
      ev = make_float4(expf(e0 - m0), expf(e1 - m1), expf(e2 - m2), expf(e3 - m3));
      dn = ev;
    }
  } else {
    for (int base = 0; base < deg; base += 64) {
      if (base + l < deg) {
        int2 p = pack[beg + base + l];
        float sv = __int_as_float(p.y);
        float4 ss = *(const float4*)(s_src + (size_t)p.x * 4);
        float e0 = ss.x + sd.x + sv; e0 = (e0 >= 0.f) ? e0 : kNeg * e0;
        float e1 = ss.y + sd.y + sv; e1 = (e1 >= 0.f) ? e1 : kNeg * e1;
        float e2 = ss.z + sd.z + sv; e2 = (e2 >= 0.f) ? e2 : kNeg * e2;
        float e3 = ss.w + sd.w + sv; e3 = (e3 >= 0.f) ? e3 : kNeg * e3;
        dn.x += expf(e0 - m0); dn.y += expf(e1 - m1);
        dn.z += expf(e2 - m2); dn.w += expf(e3 - m3);
      }
    }
  }
#pragma unroll
  for (int off = 32; off; off >>= 1) {
    dn.x += __shfl_xor(dn.x, off);
    dn.y += __shfl_xor(dn.y, off);
    dn.z += __shfl_xor(dn.z, off);
    dn.w += __shfl_xor(dn.w, off);
  }
  if (l == 0) *(float4*)(denom + (size_t)n * 4) = make_float4(dn.x, dn.y, dn.z, dn.w);
  const float i0 = 1.f / (dn.x + kEps), i1 = 1.f / (dn.y + kEps);
  const float i2 = 1.f / (dn.z + kEps), i3 = 1.f / (dn.w + kEps);
  const float myinv = (l < 32) ? ((l < 16) ? i0 : i1) : ((l < 48) ? i2 : i3);
  if (small) {
    for (int i = 0; i < deg; ++i) {
      int si = __shfl(s, i);
      float ax = __shfl(ev.x, i), ay = __shfl(ev.y, i);
      float az = __shfl(ev.z, i), aw = __shfl(ev.w, i);
      float aa = ((l < 32) ? ((l < 16) ? ax : ay) : ((l < 48) ? az : aw)) * myinv;
      unsigned u = Hb_u[(size_t)si * 64 + l];
      float2 f = __half22float2(*(const __half2*)&u);
      accx += aa * f.x;
      accy += aa * f.y;
    }
  } else {
    for (int base = 0; base < deg; base += 64) {
      int cnt = min(64, deg - base);
      int s2 = 0;
      float4 e2v = make_float4(0.f, 0.f, 0.f, 0.f);
      if (l < cnt) {
        int2 p = pack[beg + base + l];
        s2 = p.x;
        float sv = __int_as_float(p.y);
        float4 ss = *(const float4*)(s_src + (size_t)s2 * 4);
        float e0 = ss.x + sd.x + sv; e0 = (e0 >= 0.f) ? e0 : kNeg * e0;
        float e1 = ss.y + sd.y + sv; e1 = (e1 >= 0.f) ? e1 : kNeg * e1;
        float e2 = ss.z + sd.z + sv; e2 = (e2 >= 0.f) ? e2 : kNeg * e2;
        float e3 = ss.w + sd.w + sv; e3 = (e3 >= 0.f) ? e3 : kNeg * e3;
        e2v = make_float4(expf(e0 - m0), expf(e1 - m1), expf(e2 - m2), expf(e3 - m3));
      }
      for (int i = 0; i < cnt; ++i) {
        int si = __shfl(s2, i);
        float ax = __shfl(e2v.x, i), ay = __shfl(e2v.y, i);
        float az = __shfl(e2v.z, i), aw = __shfl(e2v.w, i);
        float aa = ((l < 32) ? ((l < 16) ? ax : ay) : ((l < 48) ? az : aw)) * myinv;
        unsigned u = Hb_u[(size_t)si * 64 + l];
        float2 f = __half22float2(*(const __half2*)&u);
        accx += aa * f.x;
        accy += aa * f.y;
      }
    }
  }
  if (dt) {
    *(float2*)&((float*)d_out)[(size_t)n * 128 + 2 * l] = make_float2(accx, accy);
  } else {
    __hip_bfloat162 b = __float22bfloat162_rn(make_float2(accx, accy));
    *(__hip_bfloat162*)((__hip_bfloat16*)d_out + (size_t)n * 128 + 2 * l) = b;
  }
}

// ---- K6: per-edge epilogue: msg gather + alpha (original order, coalesced) ---
__global__ __launch_bounds__(256) void k_edge(const int* __restrict__ src,
                                              const int* __restrict__ dstv,
                                              const void* __restrict__ sim1,
                                              const int* __restrict__ dflag,
                                              const float* __restrict__ s_src,
                                              const float* __restrict__ s_dst,
                                              const float* __restrict__ denom,
                                              const unsigned* __restrict__ gmax,
                                              const __half2* __restrict__ msgb2,
                                              void* __restrict__ d_out,
                                              int N, int E) {
  long long tid = (long long)blockIdx.x * 256 + threadIdx.x;
  if (tid >= (long long)E * 16) return;
  int e = (int)(tid >> 4), jp = (int)(tid & 15);
  const int dt = *dflag;
  int s = src[e];
  __half2 hv = msgb2[(size_t)s * 16 + jp];
  float2 f = __half22float2(hv);
  const size_t alpha_off = (size_t)N * 128;
  const size_t msg_off = alpha_off + (size_t)E;
  if (dt) {
    *(float2*)&((float*)d_out)[msg_off + (size_t)e * 32 + 2 * jp] = f;
  } else {
    __hip_bfloat162 b = __float22bfloat162_rn(f);
    *(__hip_bfloat162*)((__hip_bfloat16*)d_out + msg_off + (size_t)e * 32 + 2 * jp) = b;
  }
  if (jp == 0) {
    int d = dstv[e];
    float sv = dt ? ((const float*)sim1)[e] : bf2f(((const unsigned short*)sim1)[e]);
    float4 ss = *(const float4*)(s_src + (size_t)s * 4);
    float4 sd = *(const float4*)(s_dst + (size_t)d * 4);
    float4 dn = *(const float4*)(denom + (size_t)d * 4);
    float m0 = funkey(gmax[0]), m1 = funkey(gmax[1]);
    float m2 = funkey(gmax[2]), m3 = funkey(gmax[3]);
    float b = kBeta * sv;
    float e0 = ss.x + sd.x + b; e0 = (e0 >= 0.f) ? e0 : kNeg * e0;
    float e1 = ss.y + sd.y + b; e1 = (e1 >= 0.f) ? e1 : kNeg * e1;
    float e2 = ss.z + sd.z + b; e2 = (e2 >= 0.f) ? e2 : kNeg * e2;
    float e3 = ss.w + sd.w + b; e3 = (e3 >= 0.f) ? e3 : kNeg * e3;
    float am = 0.25f * (expf(e0 - m0) / (dn.x + kEps) + expf(e1 - m1) / (dn.y + kEps) +
                        expf(e2 - m2) / (dn.z + kEps) + expf(e3 - m3) / (dn.w + kEps));
    if (dt) ((float*)d_out)[alpha_off + e] = am;
    else    ((__hip_bfloat16*)d_out)[alpha_off + e] = __float2bfloat16(am);
  }
}

extern "C" void kernel_launch(void* const* d_in, const int* in_sizes, int n_in,
                              void* d_out, int out_size, void* d_ws, size_t ws_size,
                              hipStream_t stream) {
  const void* H     = d_in[0];
  const int*  ei    = (const int*)d_in[1];
  const void* sim1  = d_in[2];
  const void* W     = d_in[3];
  const void* a_src = d_in[4];
  const void* a_dst = d_in[5];
  const void* msg_w = d_in[6];
  const int N = in_sizes[0] / 256;
  const int E = in_sizes[2];
  const int NB = (N + 255) / 256;  // scan blocks (<=1024 supported)

  char* base     = (char*)d_ws;
  float* s_src   = (float*)base;  base += (size_t)N * 4 * 4;
  float* s_dst   = (float*)base;  base += (size_t)N * 4 * 4;
  __half* msgb   = (__half*)base; base += (size_t)N * DK * 2;
  __half* Hb     = (__half*)base; base += (size_t)N * 128 * 2;
  float* denom   = (float*)base;  base += (size_t)N * 4 * 4;
  unsigned short* Bhi = (unsigned short*)base; base += 32768 * 2;  // 64 KB
  unsigned short* Blo = (unsigned short*)base; base += 32768 * 2;  // 64 KB
  int* deg       = (int*)base;    base += (size_t)N * 4;   // <- zeroed from here
  unsigned* gmax = (unsigned*)base; base += 4 * 4;
  int* eflag     = (int*)base;    base += 4;
  int* dflag     = (int*)base;    base += 4;               // <- zeroed to here
  int* row_ptr   = (int*)base;    base += (size_t)(N + 2) * 4;  // +1 pad for 8B align
  int* cursor    = (int*)base;    base += (size_t)N * 4;
  int* bsum      = (int*)base;    base += 1024 * 4;
  int2* pack     = (int2*)base;   base += (size_t)E * 8;
  int* src_i     = (int*)base;    base += (size_t)E * 4;
  int* dst_i     = (int*)base;    base += (size_t)E * 4;
  float* af      = (float*)base;  base += 256 * 4;
  float* msgwf   = (float*)base;  base += 1024 * 4;

  hipMemsetAsync(deg, 0, (size_t)(N + 6) * sizeof(int), stream);

  k_detect<<<512, 256, 0, stream>>>(ei, (const unsigned*)H, eflag, dflag, E, 131072);
  k_cvt<<<(E + 255) / 256, 256, 0, stream>>>(ei, eflag, src_i, dst_i, deg, E);
  k_wparams<<<133, 256, 0, stream>>>(W, Bhi, Blo, a_src, a_dst, msg_w, af, msgwf, dflag);
  k_proj<<<(N + 63) / 64, 256, 0, stream>>>(H, Bhi, Blo, dflag, af, msgwf,
                                            s_src, s_dst, msgb, Hb, N);
  k_scan1<<<NB, 256, 0, stream>>>(deg, bsum, N);
  k_scan2<<<1, 1024, 0, stream>>>(bsum, NB);
  k_scan3<<<NB, 256, 0, stream>>>(deg, bsum, row_ptr, cursor, N);
  k_fillog<<<(E + 255) / 256, 256, 0, stream>>>(src_i, dst_i, sim1, dflag, s_src, s_dst,
                                                cursor, pack, gmax, E);
  k_out<<<(int)(((size_t)N * 64 + 255) / 256), 256, 0, stream>>>(
      row_ptr, pack, s_src, s_dst, gmax, (const unsigned*)Hb, dflag, denom, d_out, N);
  k_edge<<<(int)(((long long)E * 16 + 255) / 256), 256, 0, stream>>>(
      src_i, dst_i, sim1, dflag, s_src, s_dst, denom, gmax, (const __half2*)msgb,
      d_out, N, E);
}